// Round 1
// baseline (173.231 us; speedup 1.0000x reference)
//
#include <hip/hip_runtime.h>
#include <stdint.h>
#include <stddef.h>

#define B_ROWS 8192
#define NX 2048
#define NH 512
#define NY 1024

// prep kernel block split: elementwise cast blocks, then wq blocks
#define X_ELEMS (B_ROWS * NX)                 // 16777216 (relu+cast)
#define EW_ELEMS (X_ELEMS + NH * NX)          // + 1048576 (plain cast)
#define EW_BLOCKS (EW_ELEMS / (8 * 256))      // 8704
#define WQ_BLOCKS (NY / 4)                    // 256

typedef __attribute__((ext_vector_type(8))) short bf16x8;
typedef __attribute__((ext_vector_type(4))) float f32x4;

static __device__ __forceinline__ unsigned short f2bf(float f) {
    union { float f; unsigned int u; } c; c.f = f;
    unsigned int r = 0x7FFFu + ((c.u >> 16) & 1u);
    return (unsigned short)((c.u + r) >> 16);
}

static __device__ __forceinline__ void glld16(const void* g, void* l) {
    __builtin_amdgcn_global_load_lds(
        (const __attribute__((address_space(1))) unsigned int*)g,
        (__attribute__((address_space(3))) unsigned int*)l, 16, 0, 0);
}

// ---------------- prep: relu(x)->bf16, W_fc->bf16, W_q->bf16+rowsq, hsq=0 ----------------
__global__ __launch_bounds__(256) void prep_kernel(const float* __restrict__ x,
                                                   const float* __restrict__ wfc,
                                                   const float* __restrict__ wq,
                                                   unsigned short* __restrict__ xb,
                                                   unsigned short* __restrict__ wfcb,
                                                   unsigned short* __restrict__ wqb,
                                                   float* __restrict__ wqsq,
                                                   float* __restrict__ hsq) {
    const int bid = blockIdx.x;
    const int tid = threadIdx.x;
    if (bid < EW_BLOCKS) {
        size_t idx = ((size_t)bid * 256 + tid) * 8;
        if (idx < (size_t)X_ELEMS) {
            float4 a = *(const float4*)&x[idx];
            float4 b = *(const float4*)&x[idx + 4];
            bf16x8 o;
            o[0] = (short)f2bf(fmaxf(a.x, 0.f)); o[1] = (short)f2bf(fmaxf(a.y, 0.f));
            o[2] = (short)f2bf(fmaxf(a.z, 0.f)); o[3] = (short)f2bf(fmaxf(a.w, 0.f));
            o[4] = (short)f2bf(fmaxf(b.x, 0.f)); o[5] = (short)f2bf(fmaxf(b.y, 0.f));
            o[6] = (short)f2bf(fmaxf(b.z, 0.f)); o[7] = (short)f2bf(fmaxf(b.w, 0.f));
            *(bf16x8*)&xb[idx] = o;
        } else {
            size_t off = idx - X_ELEMS;
            float4 a = *(const float4*)&wfc[off];
            float4 b = *(const float4*)&wfc[off + 4];
            bf16x8 o;
            o[0] = (short)f2bf(a.x); o[1] = (short)f2bf(a.y);
            o[2] = (short)f2bf(a.z); o[3] = (short)f2bf(a.w);
            o[4] = (short)f2bf(b.x); o[5] = (short)f2bf(b.y);
            o[6] = (short)f2bf(b.z); o[7] = (short)f2bf(b.w);
            *(bf16x8*)&wfcb[off] = o;
        }
    } else {
        const int b2 = bid - EW_BLOCKS;        // 0..255
        const int lane = tid & 63;
        const int row = b2 * 4 + (tid >> 6);
        const float* p = wq + (size_t)row * NH + lane * 8;
        float4 a = *(const float4*)p;
        float4 b = *(const float4*)(p + 4);
        bf16x8 o;
        o[0] = (short)f2bf(a.x); o[1] = (short)f2bf(a.y);
        o[2] = (short)f2bf(a.z); o[3] = (short)f2bf(a.w);
        o[4] = (short)f2bf(b.x); o[5] = (short)f2bf(b.y);
        o[6] = (short)f2bf(b.z); o[7] = (short)f2bf(b.w);
        *(bf16x8*)&wqb[(size_t)row * NH + lane * 8] = o;
        float s = a.x*a.x + a.y*a.y + a.z*a.z + a.w*a.w
                + b.x*b.x + b.y*b.y + b.z*b.z + b.w*b.w;
        #pragma unroll
        for (int off = 32; off > 0; off >>= 1) s += __shfl_xor(s, off);
        if (lane == 0) wqsq[row] = s;
        if (tid < 32) hsq[b2 * 32 + tid] = 0.0f;   // zero-init for gemm1 atomics
    }
}

// ---------------- GEMM1: h = relu(xb @ wfcb^T + b) -> bf16 hb, fused hsq ----------------
// 512 threads = 2 k-groups x 4 waves (2x2). Tile 128(M)x128(N); wave-tile 64x64.
// In-block split-K: group g covers k in [g*1024, g*1024+1024), BK=32, double-buffered
// LDS (one barrier per iter). Epilogue: group1 dumps acc to (reused) LDS, group0
// combines + bias + relu + f2bf + hsq (shuffle+atomic).
// LDS rows are 64 B; store-side chunk swizzle f(row)=(row>>1)&3 keeps all
// b128 reads <=2-way (free).
__global__ __launch_bounds__(512, 2) void gemm1_kernel(const unsigned short* __restrict__ xb,
                                                       const unsigned short* __restrict__ wfcb,
                                                       const float* __restrict__ b_fc,
                                                       unsigned short* __restrict__ hb,
                                                       float* __restrict__ hsq) {
    __shared__ unsigned char smem[65536];
    unsigned char* AsB = smem;             // [g][buf][128 rows][32 k] bf16 = 4 x 8 KiB
    unsigned char* BsB = smem + 32768;

    const int tid = threadIdx.x;
    const int lane = tid & 63;
    const int grp = tid >> 8;              // k-half 0/1
    const int wave = (tid >> 6) & 3;       // wave within group
    const int wm = wave >> 1, wn = wave & 1;
    const int quad = lane >> 4;
    const int r = lane & 15;

    // bid = c + 8n + 32h : mtile = 8c + h (0..63), ntile = n (0..3); c = XCD slot
    const int bid = blockIdx.x;            // 0..255
    const int n0 = ((bid >> 3) & 3) * 128;
    const int m0 = (((bid & 7) << 3) | (bid >> 5)) * 128;
    const int kbase = grp * (NX / 2);

    f32x4 acc[4][4];
    #pragma unroll
    for (int i = 0; i < 4; ++i)
        #pragma unroll
        for (int j = 0; j < 4; ++j) acc[i][j] = (f32x4)(0.0f);

    const int lrow = lane >> 2;                       // 0..15 (row within 16-row chunk)
    const int gch = (lane & 3) ^ ((lrow >> 1) & 3);   // swizzled 16B chunk
    const char* xbB = (const char*)xb;
    const char* wfB = (const char*)wfcb;
    const int fsw = (quad ^ ((r >> 1) & 3)) * 16;     // fragment chunk byte offset

    auto stage = [&](int buf, int k0) {
        const int sb = grp * 16384 + buf * 8192;
        #pragma unroll
        for (int c = 0; c < 2; ++c) {
            int R0 = wave * 32 + c * 16;
            glld16(xbB + (size_t)(m0 + R0 + lrow) * (NX * 2) + k0 * 2 + gch * 16,
                   AsB + sb + R0 * 64);
            glld16(wfB + (size_t)(n0 + R0 + lrow) * (NX * 2) + k0 * 2 + gch * 16,
                   BsB + sb + R0 * 64);
        }
    };

    stage(0, kbase);
    #pragma unroll 1
    for (int it = 0; it < 32; ++it) {
        __syncthreads();
        if (it + 1 < 32) stage((it + 1) & 1, kbase + it * 32 + 32);
        const unsigned char* ab = AsB + grp * 16384 + (it & 1) * 8192;
        const unsigned char* bb = BsB + grp * 16384 + (it & 1) * 8192;
        bf16x8 af[4], bfv[4];
        #pragma unroll
        for (int i = 0; i < 4; ++i)
            af[i] = *(const bf16x8*)(ab + (wm * 64 + i * 16 + r) * 64 + fsw);
        #pragma unroll
        for (int j = 0; j < 4; ++j)
            bfv[j] = *(const bf16x8*)(bb + (wn * 64 + j * 16 + r) * 64 + fsw);
        #pragma unroll
        for (int i = 0; i < 4; ++i)
            #pragma unroll
            for (int j = 0; j < 4; ++j)
                acc[i][j] = __builtin_amdgcn_mfma_f32_16x16x32_bf16(af[i], bfv[j], acc[i][j], 0, 0, 0);
    }

    // ---- combine the two k-halves through LDS, epilogue by group 0 ----
    float* smemF = (float*)smem;
    __syncthreads();
    if (grp == 1) {
        #pragma unroll
        for (int i = 0; i < 4; ++i) {
            #pragma unroll
            for (int j = 0; j < 4; ++j) {
                int cl = wn * 64 + j * 16 + r;
                int rowb = wm * 64 + i * 16 + quad * 4;
                *(f32x4*)(smemF + cl * 128 + (rowb ^ ((cl & 7) << 2))) = acc[i][j];
            }
        }
    }
    __syncthreads();
    if (grp == 0) {
        float p[4][4];
        #pragma unroll
        for (int i = 0; i < 4; ++i)
            #pragma unroll
            for (int rr = 0; rr < 4; ++rr) p[i][rr] = 0.0f;

        #pragma unroll
        for (int i = 0; i < 4; ++i) {
            #pragma unroll
            for (int j = 0; j < 4; ++j) {
                int cl = wn * 64 + j * 16 + r;
                int rowb = wm * 64 + i * 16 + quad * 4;
                f32x4 o = *(const f32x4*)(smemF + cl * 128 + (rowb ^ ((cl & 7) << 2)));
                int col = n0 + cl;
                float bias = b_fc[col];
                #pragma unroll
                for (int rr = 0; rr < 4; ++rr) {
                    float v = fmaxf(acc[i][j][rr] + o[rr] + bias, 0.0f);
                    hb[(size_t)(m0 + rowb + rr) * NH + col] = f2bf(v);
                    p[i][rr] += v * v;
                }
            }
        }
        #pragma unroll
        for (int mask = 1; mask < 16; mask <<= 1) {
            #pragma unroll
            for (int i = 0; i < 4; ++i)
                #pragma unroll
                for (int rr = 0; rr < 4; ++rr)
                    p[i][rr] += __shfl_xor(p[i][rr], mask);
        }
        if (r == 0) {
            #pragma unroll
            for (int i = 0; i < 4; ++i)
                #pragma unroll
                for (int rr = 0; rr < 4; ++rr)
                    atomicAdd(&hsq[m0 + wm * 64 + i * 16 + quad * 4 + rr], p[i][rr]);
        }
    }
}

// ---------------- GEMM2 fused with per-row LSE (single pass over out) ----------------
// NU=1  =>  t = -log1p(d)  =>  exp(t) = 1/(1+d): the softmax denominator is a
// v_rcp on a register value -- no exp, no second pass, no max (t <= 0).
// Block = 32 rows x ALL 1024 cols so the row-reduction is in-block.
// 512 threads = 8 waves, wave w owns cols [w*128, w*128+128): acc 2x8 f32x4.
// K=512, BK=32, A+B double-buffered; B slab is the full 1024x32 bf16 per iter
// (2 x 64 KiB) + A (2 x 2 KiB) = 132 KiB LDS, 1 block/CU. Same 64-B-row
// chunk-swizzle scheme as gemm1 (glld16 staging, <=2-way b128 reads).
// Epilogue: d -> rcp accumulates srow, t overwrites acc in-register;
// shfl_xor col-reduce -> 8-wave LDS reduce -> log(S) -> subtract -> store.
__global__ __launch_bounds__(512, 2) void gemm2_kernel(const unsigned short* __restrict__ hb,
                                                       const unsigned short* __restrict__ wqb,
                                                       const float* __restrict__ hsq,
                                                       const float* __restrict__ wqsq,
                                                       float* __restrict__ out) {
    __shared__ unsigned char smem[135168];   // A dbuf 4 KiB + B dbuf 128 KiB
    char* AsB = (char*)smem;                 // [buf][32 rows][64 B]
    char* BsB = (char*)smem + 4096;          // [buf][1024 rows][64 B]

    const int tid = threadIdx.x;
    const int lane = tid & 63;
    const int wave = tid >> 6;               // 0..7 -> col slab [wave*128, +128)
    const int quad = lane >> 4;
    const int r = lane & 15;
    const int m0 = blockIdx.x * 32;          // 256 blocks

    f32x4 acc[2][8];
    #pragma unroll
    for (int i = 0; i < 2; ++i)
        #pragma unroll
        for (int j = 0; j < 8; ++j) acc[i][j] = (f32x4)(0.0f);

    const int lrow = lane >> 2;                       // 0..15
    const int gch = (lane & 3) ^ ((lrow >> 1) & 3);   // swizzled 16B chunk
    const char* bsrc = (const char*)wqb + (size_t)(wave * 128 + lrow) * (NH * 2) + gch * 16;
    const char* asrc = (const char*)hb + (size_t)(m0 + wave * 16 + lrow) * (NH * 2) + gch * 16;
    const int fsw = (quad ^ ((r >> 1) & 3)) * 16;

    auto stage = [&](int buf, int k0) {
        #pragma unroll
        for (int c = 0; c < 8; ++c)                   // 8x16 = this wave's 128 B-rows
            glld16(bsrc + (size_t)k0 * 2 + c * 16384,
                   BsB + buf * 65536 + wave * 8192 + c * 1024);
        if (wave < 2)                                 // 2x16 = 32 A-rows
            glld16(asrc + (size_t)k0 * 2, AsB + buf * 2048 + wave * 1024);
    };

    stage(0, 0);
    #pragma unroll 1
    for (int it = 0; it < NH / 32; ++it) {            // 16 iters
        __syncthreads();
        if (it + 1 < NH / 32) stage((it + 1) & 1, it * 32 + 32);
        const char* ab = AsB + (it & 1) * 2048;
        const char* bb = BsB + (it & 1) * 65536 + wave * 8192;
        bf16x8 af[2], bfv[8];
        #pragma unroll
        for (int i = 0; i < 2; ++i)
            af[i] = *(const bf16x8*)(ab + (i * 16 + r) * 64 + fsw);
        #pragma unroll
        for (int j = 0; j < 8; ++j)
            bfv[j] = *(const bf16x8*)(bb + (j * 16 + r) * 64 + fsw);
        #pragma unroll
        for (int i = 0; i < 2; ++i)
            #pragma unroll
            for (int j = 0; j < 8; ++j)
                acc[i][j] = __builtin_amdgcn_mfma_f32_16x16x32_bf16(af[i], bfv[j], acc[i][j], 0, 0, 0);
    }

    // ---- epilogue: d, t, and row-sums of exp(t) = 1/(1+d) ----
    float hs_[2][4];
    #pragma unroll
    for (int i = 0; i < 2; ++i)
        #pragma unroll
        for (int rr = 0; rr < 4; ++rr)
            hs_[i][rr] = hsq[m0 + i * 16 + quad * 4 + rr];

    float srow[2][4];
    #pragma unroll
    for (int i = 0; i < 2; ++i)
        #pragma unroll
        for (int rr = 0; rr < 4; ++rr) srow[i][rr] = 0.0f;

    #pragma unroll
    for (int j = 0; j < 8; ++j) {
        float wqv = wqsq[wave * 128 + j * 16 + r];
        #pragma unroll
        for (int i = 0; i < 2; ++i) {
            #pragma unroll
            for (int rr = 0; rr < 4; ++rr) {
                float d = hs_[i][rr] - 2.0f * acc[i][j][rr] + wqv;
                d = fmaxf(d, 0.0f);
                float onepd = 1.0f + d;
                srow[i][rr] += __builtin_amdgcn_rcpf(onepd);
                acc[i][j][rr] = -__logf(onepd);       // keep t in-register
            }
        }
    }
    // reduce over the 16 cols held by this quad-group (r bits only)
    #pragma unroll
    for (int mask = 1; mask < 16; mask <<= 1)
        #pragma unroll
        for (int i = 0; i < 2; ++i)
            #pragma unroll
            for (int rr = 0; rr < 4; ++rr)
                srow[i][rr] += __shfl_xor(srow[i][rr], mask);

    // cross-wave reduce through (reused) LDS
    float* smemF = (float*)smem;
    __syncthreads();                                  // done with As/Bs
    if (r == 0) {
        #pragma unroll
        for (int i = 0; i < 2; ++i)
            #pragma unroll
            for (int rr = 0; rr < 4; ++rr)
                smemF[wave * 32 + i * 16 + quad * 4 + rr] = srow[i][rr];
    }
    __syncthreads();
    if (tid < 32) {
        float S = 0.0f;
        #pragma unroll
        for (int w = 0; w < 8; ++w) S += smemF[w * 32 + tid];
        smemF[256 + tid] = __logf(S);
    }
    __syncthreads();

    #pragma unroll
    for (int i = 0; i < 2; ++i) {
        #pragma unroll
        for (int rr = 0; rr < 4; ++rr) {
            float l = smemF[256 + i * 16 + quad * 4 + rr];
            size_t rowoff = (size_t)(m0 + i * 16 + quad * 4 + rr) * NY + wave * 128 + r;
            #pragma unroll
            for (int j = 0; j < 8; ++j)
                out[rowoff + j * 16] = acc[i][j][rr] - l;
        }
    }
}

extern "C" void kernel_launch(void* const* d_in, const int* in_sizes, int n_in,
                              void* d_out, int out_size, void* d_ws, size_t ws_size,
                              hipStream_t stream) {
    const float* x    = (const float*)d_in[0];
    const float* W_fc = (const float*)d_in[1];
    const float* b_fc = (const float*)d_in[2];
    const float* W_q  = (const float*)d_in[3];
    float* out = (float*)d_out;

    char* ws = (char*)d_ws;
    unsigned short* xb   = (unsigned short*)(ws);                        // 32 MiB
    unsigned short* wfcb = (unsigned short*)(ws + 33554432);             // 2 MiB
    unsigned short* wqb  = (unsigned short*)(ws + 35651584);             // 1 MiB
    float*          wqsq = (float*)(ws + 36700160);                      // 4 KiB
    unsigned short* hb   = (unsigned short*)(ws + 36704256);             // 8 MiB
    float*          hsq  = (float*)(ws + 45092864);                      // 32 KiB

    prep_kernel<<<EW_BLOCKS + WQ_BLOCKS, 256, 0, stream>>>(x, W_fc, W_q, xb, wfcb, wqb, wqsq, hsq);
    gemm1_kernel<<<256, 512, 0, stream>>>(xb, wfcb, b_fc, hb, hsq);
    gemm2_kernel<<<B_ROWS / 32, 512, 0, stream>>>(hb, wqb, hsq, wqsq, out);
}

// Round 2
// 172.679 us; speedup vs baseline: 1.0032x; 1.0032x over previous
//
#include <hip/hip_runtime.h>
#include <stdint.h>
#include <stddef.h>

#define B_ROWS 8192
#define NX 2048
#define NH 512
#define NY 1024

// prep kernel block split: elementwise cast blocks, then wq blocks
#define X_ELEMS (B_ROWS * NX)                 // 16777216 (relu+cast)
#define EW_ELEMS (X_ELEMS + NH * NX)          // + 1048576 (plain cast)
#define EW_BLOCKS (EW_ELEMS / (8 * 256))      // 8704
#define WQ_BLOCKS (NY / 4)                    // 256

typedef __attribute__((ext_vector_type(8))) short bf16x8;
typedef __attribute__((ext_vector_type(4))) float f32x4;

static __device__ __forceinline__ unsigned short f2bf(float f) {
    union { float f; unsigned int u; } c; c.f = f;
    unsigned int r = 0x7FFFu + ((c.u >> 16) & 1u);
    return (unsigned short)((c.u + r) >> 16);
}

static __device__ __forceinline__ void glld16(const void* g, void* l) {
    __builtin_amdgcn_global_load_lds(
        (const __attribute__((address_space(1))) unsigned int*)g,
        (__attribute__((address_space(3))) unsigned int*)l, 16, 0, 0);
}

// ---------------- prep: relu(x)->bf16, W_fc->bf16, W_q->bf16+rowsq, hsq=0 ----------------
__global__ __launch_bounds__(256) void prep_kernel(const float* __restrict__ x,
                                                   const float* __restrict__ wfc,
                                                   const float* __restrict__ wq,
                                                   unsigned short* __restrict__ xb,
                                                   unsigned short* __restrict__ wfcb,
                                                   unsigned short* __restrict__ wqb,
                                                   float* __restrict__ wqsq,
                                                   float* __restrict__ hsq) {
    const int bid = blockIdx.x;
    const int tid = threadIdx.x;
    if (bid < EW_BLOCKS) {
        size_t idx = ((size_t)bid * 256 + tid) * 8;
        if (idx < (size_t)X_ELEMS) {
            float4 a = *(const float4*)&x[idx];
            float4 b = *(const float4*)&x[idx + 4];
            bf16x8 o;
            o[0] = (short)f2bf(fmaxf(a.x, 0.f)); o[1] = (short)f2bf(fmaxf(a.y, 0.f));
            o[2] = (short)f2bf(fmaxf(a.z, 0.f)); o[3] = (short)f2bf(fmaxf(a.w, 0.f));
            o[4] = (short)f2bf(fmaxf(b.x, 0.f)); o[5] = (short)f2bf(fmaxf(b.y, 0.f));
            o[6] = (short)f2bf(fmaxf(b.z, 0.f)); o[7] = (short)f2bf(fmaxf(b.w, 0.f));
            *(bf16x8*)&xb[idx] = o;
        } else {
            size_t off = idx - X_ELEMS;
            float4 a = *(const float4*)&wfc[off];
            float4 b = *(const float4*)&wfc[off + 4];
            bf16x8 o;
            o[0] = (short)f2bf(a.x); o[1] = (short)f2bf(a.y);
            o[2] = (short)f2bf(a.z); o[3] = (short)f2bf(a.w);
            o[4] = (short)f2bf(b.x); o[5] = (short)f2bf(b.y);
            o[6] = (short)f2bf(b.z); o[7] = (short)f2bf(b.w);
            *(bf16x8*)&wfcb[off] = o;
        }
    } else {
        const int b2 = bid - EW_BLOCKS;        // 0..255
        const int lane = tid & 63;
        const int row = b2 * 4 + (tid >> 6);
        const float* p = wq + (size_t)row * NH + lane * 8;
        float4 a = *(const float4*)p;
        float4 b = *(const float4*)(p + 4);
        bf16x8 o;
        o[0] = (short)f2bf(a.x); o[1] = (short)f2bf(a.y);
        o[2] = (short)f2bf(a.z); o[3] = (short)f2bf(a.w);
        o[4] = (short)f2bf(b.x); o[5] = (short)f2bf(b.y);
        o[6] = (short)f2bf(b.z); o[7] = (short)f2bf(b.w);
        *(bf16x8*)&wqb[(size_t)row * NH + lane * 8] = o;
        float s = a.x*a.x + a.y*a.y + a.z*a.z + a.w*a.w
                + b.x*b.x + b.y*b.y + b.z*b.z + b.w*b.w;
        #pragma unroll
        for (int off = 32; off > 0; off >>= 1) s += __shfl_xor(s, off);
        if (lane == 0) wqsq[row] = s;
        if (tid < 32) hsq[b2 * 32 + tid] = 0.0f;   // zero-init for gemm1 atomics
    }
}

// ---------------- GEMM1: h = relu(xb @ wfcb^T + b) -> bf16 hb, fused hsq ----------------
// 512 threads = 2 k-groups x 4 waves (2x2). Tile 128(M)x128(N); wave-tile 64x64.
// In-block split-K: group g covers k in [g*1024, g*1024+1024), BK=32, double-buffered
// LDS (one barrier per iter). Epilogue: group1 dumps acc to (reused) LDS, group0
// combines + bias + relu + f2bf + hsq (shuffle+atomic).
// LDS rows are 64 B; store-side chunk swizzle f(row)=(row>>1)&3 keeps all
// b128 reads <=2-way (free).
__global__ __launch_bounds__(512, 2) void gemm1_kernel(const unsigned short* __restrict__ xb,
                                                       const unsigned short* __restrict__ wfcb,
                                                       const float* __restrict__ b_fc,
                                                       unsigned short* __restrict__ hb,
                                                       float* __restrict__ hsq) {
    __shared__ unsigned char smem[65536];
    unsigned char* AsB = smem;             // [g][buf][128 rows][32 k] bf16 = 4 x 8 KiB
    unsigned char* BsB = smem + 32768;

    const int tid = threadIdx.x;
    const int lane = tid & 63;
    const int grp = tid >> 8;              // k-half 0/1
    const int wave = (tid >> 6) & 3;       // wave within group
    const int wm = wave >> 1, wn = wave & 1;
    const int quad = lane >> 4;
    const int r = lane & 15;

    // bid = c + 8n + 32h : mtile = 8c + h (0..63), ntile = n (0..3); c = XCD slot
    const int bid = blockIdx.x;            // 0..255
    const int n0 = ((bid >> 3) & 3) * 128;
    const int m0 = (((bid & 7) << 3) | (bid >> 5)) * 128;
    const int kbase = grp * (NX / 2);

    f32x4 acc[4][4];
    #pragma unroll
    for (int i = 0; i < 4; ++i)
        #pragma unroll
        for (int j = 0; j < 4; ++j) acc[i][j] = (f32x4)(0.0f);

    const int lrow = lane >> 2;                       // 0..15 (row within 16-row chunk)
    const int gch = (lane & 3) ^ ((lrow >> 1) & 3);   // swizzled 16B chunk
    const char* xbB = (const char*)xb;
    const char* wfB = (const char*)wfcb;
    const int fsw = (quad ^ ((r >> 1) & 3)) * 16;     // fragment chunk byte offset

    auto stage = [&](int buf, int k0) {
        const int sb = grp * 16384 + buf * 8192;
        #pragma unroll
        for (int c = 0; c < 2; ++c) {
            int R0 = wave * 32 + c * 16;
            glld16(xbB + (size_t)(m0 + R0 + lrow) * (NX * 2) + k0 * 2 + gch * 16,
                   AsB + sb + R0 * 64);
            glld16(wfB + (size_t)(n0 + R0 + lrow) * (NX * 2) + k0 * 2 + gch * 16,
                   BsB + sb + R0 * 64);
        }
    };

    stage(0, kbase);
    #pragma unroll 1
    for (int it = 0; it < 32; ++it) {
        __syncthreads();
        if (it + 1 < 32) stage((it + 1) & 1, kbase + it * 32 + 32);
        const unsigned char* ab = AsB + grp * 16384 + (it & 1) * 8192;
        const unsigned char* bb = BsB + grp * 16384 + (it & 1) * 8192;
        bf16x8 af[4], bfv[4];
        #pragma unroll
        for (int i = 0; i < 4; ++i)
            af[i] = *(const bf16x8*)(ab + (wm * 64 + i * 16 + r) * 64 + fsw);
        #pragma unroll
        for (int j = 0; j < 4; ++j)
            bfv[j] = *(const bf16x8*)(bb + (wn * 64 + j * 16 + r) * 64 + fsw);
        #pragma unroll
        for (int i = 0; i < 4; ++i)
            #pragma unroll
            for (int j = 0; j < 4; ++j)
                acc[i][j] = __builtin_amdgcn_mfma_f32_16x16x32_bf16(af[i], bfv[j], acc[i][j], 0, 0, 0);
    }

    // ---- combine the two k-halves through LDS, epilogue by group 0 ----
    float* smemF = (float*)smem;
    __syncthreads();
    if (grp == 1) {
        #pragma unroll
        for (int i = 0; i < 4; ++i) {
            #pragma unroll
            for (int j = 0; j < 4; ++j) {
                int cl = wn * 64 + j * 16 + r;
                int rowb = wm * 64 + i * 16 + quad * 4;
                *(f32x4*)(smemF + cl * 128 + (rowb ^ ((cl & 7) << 2))) = acc[i][j];
            }
        }
    }
    __syncthreads();
    if (grp == 0) {
        float p[4][4];
        #pragma unroll
        for (int i = 0; i < 4; ++i)
            #pragma unroll
            for (int rr = 0; rr < 4; ++rr) p[i][rr] = 0.0f;

        #pragma unroll
        for (int i = 0; i < 4; ++i) {
            #pragma unroll
            for (int j = 0; j < 4; ++j) {
                int cl = wn * 64 + j * 16 + r;
                int rowb = wm * 64 + i * 16 + quad * 4;
                f32x4 o = *(const f32x4*)(smemF + cl * 128 + (rowb ^ ((cl & 7) << 2)));
                int col = n0 + cl;
                float bias = b_fc[col];
                #pragma unroll
                for (int rr = 0; rr < 4; ++rr) {
                    float v = fmaxf(acc[i][j][rr] + o[rr] + bias, 0.0f);
                    hb[(size_t)(m0 + rowb + rr) * NH + col] = f2bf(v);
                    p[i][rr] += v * v;
                }
            }
        }
        #pragma unroll
        for (int mask = 1; mask < 16; mask <<= 1) {
            #pragma unroll
            for (int i = 0; i < 4; ++i)
                #pragma unroll
                for (int rr = 0; rr < 4; ++rr)
                    p[i][rr] += __shfl_xor(p[i][rr], mask);
        }
        if (r == 0) {
            #pragma unroll
            for (int i = 0; i < 4; ++i)
                #pragma unroll
                for (int rr = 0; rr < 4; ++rr)
                    atomicAdd(&hsq[m0 + wm * 64 + i * 16 + quad * 4 + rr], p[i][rr]);
        }
    }
}

// ---------------- GEMM2 fused with per-row LSE (single pass over out) ----------------
// NU=1  =>  t = -log1p(d)  =>  exp(t) = 1/(1+d): softmax denominator is a v_rcp
// on a register value -- no exp, no second out pass, no max (t <= 0).
// R1 post-mortem: 512thr/132KiB = 2 waves/SIMD -> barrier/latency-bound (~40us).
// R2 fix: SAME LDS footprint, 1024 threads = 16 waves = 4 waves/SIMD.
// Block = 32 rows x ALL 1024 cols; wave w owns cols [w*64, w*64+64):
// acc 2x4 f32x4 (~32 VGPR, total ~80 -> 4 waves/SIMD at <=128 VGPR).
// K=512, BK=32 double-buffered: B slab 1024x32 bf16 (2x64 KiB) + A (2x2 KiB)
// = 132 KiB, 1 block/CU. 64-B-row chunk swizzle as gemm1 (<=2-way b128 reads).
__global__ __launch_bounds__(1024, 4) void gemm2_kernel(const unsigned short* __restrict__ hb,
                                                        const unsigned short* __restrict__ wqb,
                                                        const float* __restrict__ hsq,
                                                        const float* __restrict__ wqsq,
                                                        float* __restrict__ out) {
    __shared__ unsigned char smem[135168];   // A dbuf 4 KiB + B dbuf 128 KiB
    char* AsB = (char*)smem;                 // [buf][32 rows][64 B]
    char* BsB = (char*)smem + 4096;          // [buf][1024 rows][64 B]

    const int tid = threadIdx.x;
    const int lane = tid & 63;
    const int wave = tid >> 6;               // 0..15 -> col slab [wave*64, +64)
    const int quad = lane >> 4;
    const int r = lane & 15;
    const int m0 = blockIdx.x * 32;          // 256 blocks

    f32x4 acc[2][4];
    #pragma unroll
    for (int i = 0; i < 2; ++i)
        #pragma unroll
        for (int j = 0; j < 4; ++j) acc[i][j] = (f32x4)(0.0f);

    const int lrow = lane >> 2;                       // 0..15
    const int gch = (lane & 3) ^ ((lrow >> 1) & 3);   // swizzled 16B chunk
    const char* bsrc = (const char*)wqb + (size_t)(wave * 64 + lrow) * (NH * 2) + gch * 16;
    const char* asrc = (const char*)hb + (size_t)(m0 + wave * 16 + lrow) * (NH * 2) + gch * 16;
    const int fsw = (quad ^ ((r >> 1) & 3)) * 16;

    auto stage = [&](int buf, int k0) {
        #pragma unroll
        for (int c = 0; c < 4; ++c)                   // 4x16 = this wave's 64 B-rows
            glld16(bsrc + (size_t)k0 * 2 + c * 16 * (NH * 2),
                   BsB + buf * 65536 + (wave * 64 + c * 16) * 64);
        if (wave < 2)                                 // 2x16 = 32 A-rows
            glld16(asrc + (size_t)k0 * 2, AsB + buf * 2048 + wave * 1024);
    };

    stage(0, 0);
    #pragma unroll 1
    for (int it = 0; it < NH / 32; ++it) {            // 16 iters
        __syncthreads();
        if (it + 1 < NH / 32) stage((it + 1) & 1, it * 32 + 32);
        const char* ab = AsB + (it & 1) * 2048;
        const char* bb = BsB + (it & 1) * 65536 + wave * 4096;
        bf16x8 af[2], bfv[4];
        #pragma unroll
        for (int i = 0; i < 2; ++i)
            af[i] = *(const bf16x8*)(ab + (i * 16 + r) * 64 + fsw);
        #pragma unroll
        for (int j = 0; j < 4; ++j)
            bfv[j] = *(const bf16x8*)(bb + (j * 16 + r) * 64 + fsw);
        #pragma unroll
        for (int i = 0; i < 2; ++i)
            #pragma unroll
            for (int j = 0; j < 4; ++j)
                acc[i][j] = __builtin_amdgcn_mfma_f32_16x16x32_bf16(af[i], bfv[j], acc[i][j], 0, 0, 0);
    }

    // ---- epilogue: d, t, and row-sums of exp(t) = 1/(1+d) ----
    float hs_[2][4];
    #pragma unroll
    for (int i = 0; i < 2; ++i)
        #pragma unroll
        for (int rr = 0; rr < 4; ++rr)
            hs_[i][rr] = hsq[m0 + i * 16 + quad * 4 + rr];

    float srow[2][4];
    #pragma unroll
    for (int i = 0; i < 2; ++i)
        #pragma unroll
        for (int rr = 0; rr < 4; ++rr) srow[i][rr] = 0.0f;

    #pragma unroll
    for (int j = 0; j < 4; ++j) {
        float wqv = wqsq[wave * 64 + j * 16 + r];
        #pragma unroll
        for (int i = 0; i < 2; ++i) {
            #pragma unroll
            for (int rr = 0; rr < 4; ++rr) {
                float d = hs_[i][rr] - 2.0f * acc[i][j][rr] + wqv;
                d = fmaxf(d, 0.0f);
                float onepd = 1.0f + d;
                srow[i][rr] += __builtin_amdgcn_rcpf(onepd);
                acc[i][j][rr] = -__logf(onepd);       // keep t in-register
            }
        }
    }
    // reduce over the 16 cols held by this quad-group (r bits only)
    #pragma unroll
    for (int mask = 1; mask < 16; mask <<= 1)
        #pragma unroll
        for (int i = 0; i < 2; ++i)
            #pragma unroll
            for (int rr = 0; rr < 4; ++rr)
                srow[i][rr] += __shfl_xor(srow[i][rr], mask);

    // cross-wave reduce through (reused) LDS
    float* smemF = (float*)smem;
    __syncthreads();                                  // done with As/Bs
    if (r == 0) {
        #pragma unroll
        for (int i = 0; i < 2; ++i)
            #pragma unroll
            for (int rr = 0; rr < 4; ++rr)
                smemF[wave * 32 + i * 16 + quad * 4 + rr] = srow[i][rr];
    }
    __syncthreads();
    if (tid < 32) {
        float S = 0.0f;
        #pragma unroll
        for (int w = 0; w < 16; ++w) S += smemF[w * 32 + tid];
        smemF[512 + tid] = __logf(S);
    }
    __syncthreads();

    #pragma unroll
    for (int i = 0; i < 2; ++i) {
        #pragma unroll
        for (int rr = 0; rr < 4; ++rr) {
            float l = smemF[512 + i * 16 + quad * 4 + rr];
            size_t rowoff = (size_t)(m0 + i * 16 + quad * 4 + rr) * NY + wave * 64 + r;
            #pragma unroll
            for (int j = 0; j < 4; ++j)
                out[rowoff + j * 16] = acc[i][j][rr] - l;
        }
    }
}

extern "C" void kernel_launch(void* const* d_in, const int* in_sizes, int n_in,
                              void* d_out, int out_size, void* d_ws, size_t ws_size,
                              hipStream_t stream) {
    const float* x    = (const float*)d_in[0];
    const float* W_fc = (const float*)d_in[1];
    const float* b_fc = (const float*)d_in[2];
    const float* W_q  = (const float*)d_in[3];
    float* out = (float*)d_out;

    char* ws = (char*)d_ws;
    unsigned short* xb   = (unsigned short*)(ws);                        // 32 MiB
    unsigned short* wfcb = (unsigned short*)(ws + 33554432);             // 2 MiB
    unsigned short* wqb  = (unsigned short*)(ws + 35651584);             // 1 MiB
    float*          wqsq = (float*)(ws + 36700160);                      // 4 KiB
    unsigned short* hb   = (unsigned short*)(ws + 36704256);             // 8 MiB
    float*          hsq  = (float*)(ws + 45092864);                      // 32 KiB

    prep_kernel<<<EW_BLOCKS + WQ_BLOCKS, 256, 0, stream>>>(x, W_fc, W_q, xb, wfcb, wqb, wqsq, hsq);
    gemm1_kernel<<<256, 512, 0, stream>>>(xb, wfcb, b_fc, hb, hsq);
    gemm2_kernel<<<B_ROWS / 32, 1024, 0, stream>>>(hb, wqb, hsq, wqsq, out);
}